// Round 1
// baseline (3790.840 us; speedup 1.0000x reference)
//
#include <hip/hip_runtime.h>
#include <hip/hip_bf16.h>
#include <math.h>

typedef __hip_bfloat16 bf16;
typedef __attribute__((ext_vector_type(4))) float floatx4;
typedef __attribute__((ext_vector_type(8))) short shortx8;

#define T_TOK 1154
#define C_DIM 768
#define H_HEADS 12
#define NLOC 577
#define SP 1160          // scores pitch (>= 1154)
#define OUT_PER 1769472  // 2*576*1536

// per-layer weight element counts (row-major [O,K])
#define NQ  1769472ull   // 2304*768
#define NP  589824ull    // 768*768
#define NF1 2359296ull   // 3072*768
#define NF2 2359296ull   // 768*3072
#define NWTOT 7077888ull // NQ+NP+NF1+NF2
// offsets into per-layer bf16 weight buffer
#define WQ  0ull
#define WP  1769472ull
#define WF1 2359296ull
#define WF2 4718592ull

static __device__ __forceinline__ float b2f(bf16 v) { return __bfloat162float(v); }
static __device__ __forceinline__ bf16 f2b(float v) { return __float2bfloat16(v); }

// ---------------- init: x (f32) -> f32 residual, camera token splice ----------------
__global__ void k_init(const float* __restrict__ xin, const float* __restrict__ cam,
                       float* __restrict__ xF, int total) {
    int idx = blockIdx.x * 256 + threadIdx.x;
    if (idx >= total) return;
    int t = idx / C_DIM, c = idx - t * C_DIM;
    int s = t / NLOC, n = t - s * NLOC;
    float v = (n == 0) ? cam[s * C_DIM + c] : xin[idx];
    xF[idx] = v;
}

// ---------------- cast f32 residual -> bf16 snapshot ----------------
__global__ void k_cast(const float* __restrict__ src, bf16* __restrict__ dst, int total) {
    int idx = blockIdx.x * 256 + threadIdx.x;
    if (idx < total) dst[idx] = f2b(src[idx]);
}

// ---------------- per-layer weight convert: f32 -> bf16 (4 mats fused) ----------------
__global__ __launch_bounds__(256) void k_wconv(
    const float* __restrict__ wq, const float* __restrict__ wp,
    const float* __restrict__ wf1, const float* __restrict__ wf2,
    bf16* __restrict__ dst) {
    size_t e = ((size_t)blockIdx.x * 256 + threadIdx.x) * 8;
    if (e >= NWTOT) return;
    const float* src; size_t off;
    if (e < WP)       { src = wq;  off = e; }
    else if (e < WF1) { src = wp;  off = e - WP; }
    else if (e < WF2) { src = wf1; off = e - WF1; }
    else              { src = wf2; off = e - WF2; }
    float4 a = *(const float4*)(src + off);
    float4 b = *(const float4*)(src + off + 4);
    bf16 pk[8];
    pk[0] = f2b(a.x); pk[1] = f2b(a.y); pk[2] = f2b(a.z); pk[3] = f2b(a.w);
    pk[4] = f2b(b.x); pk[5] = f2b(b.y); pk[6] = f2b(b.z); pk[7] = f2b(b.w);
    *(shortx8*)(dst + e) = *(shortx8*)pk;
}

// ---------------- LayerNorm: f32 residual -> bf16 ----------------
__global__ __launch_bounds__(256) void k_ln(const float* __restrict__ xF,
                                            const float* __restrict__ w, const float* __restrict__ b,
                                            bf16* __restrict__ out) {
    int t = blockIdx.x;
    const float* xr = xF + (size_t)t * C_DIM;
    float s = 0.f, s2 = 0.f;
    for (int c = threadIdx.x; c < C_DIM; c += 256) { float v = xr[c]; s += v; s2 += v * v; }
    __shared__ float red[8];
    for (int o = 32; o; o >>= 1) { s += __shfl_xor(s, o, 64); s2 += __shfl_xor(s2, o, 64); }
    int wv = threadIdx.x >> 6;
    if ((threadIdx.x & 63) == 0) { red[wv] = s; red[4 + wv] = s2; }
    __syncthreads();
    s = red[0] + red[1] + red[2] + red[3];
    s2 = red[4] + red[5] + red[6] + red[7];
    float mean = s * (1.0f / C_DIM);
    float var = s2 * (1.0f / C_DIM) - mean * mean;
    if (var < 0.f) var = 0.f;
    float inv = rsqrtf(var + 1e-6f);
    bf16* orow = out + (size_t)t * C_DIM;
    for (int c = threadIdx.x; c < C_DIM; c += 256) {
        float v = (xr[c] - mean) * inv * w[c] + b[c];
        orow[c] = f2b(v);
    }
}

// ---------------- GEMM: out[M,N] = A[M,K](bf16) x Bt[N,K](bf16)^T ----------------
// 64x64 tile, K-step 64, XCD-bijective-swizzled 1D grid.
// mode 1: outB = gelu_exact(acc + bias)         (bf16 out)
// mode 2: xio += gamma * (acc + bias)           (f32 residual in-place)
// mode 3: outB = acc + bias                     (bf16 out)
__global__ __launch_bounds__(256) void k_gemm(
    const bf16* __restrict__ A, const bf16* __restrict__ Bt,
    const float* __restrict__ bias, const float* __restrict__ gamma,
    bf16* __restrict__ outB, float* __restrict__ xio,
    int M, int N, int K, int mB, int mode) {
    __shared__ short At[64 * 72];
    __shared__ short Bs[64 * 72];
    // bijective XCD swizzle (m204 form): each XCD owns a contiguous lid2 chunk
    int nwg = gridDim.x;
    int lid = blockIdx.x;
    int qd = nwg >> 3, rm = nwg & 7;
    int xcd = lid & 7, pos = lid >> 3;
    int lid2 = (xcd < rm ? xcd * (qd + 1) : rm * (qd + 1) + (xcd - rm) * qd) + pos;
    int mI = lid2 % mB, nI = lid2 / mB;
    int m0 = mI * 64, n0 = nI * 64;
    int tid = threadIdx.x;
    int wv = tid >> 6, lane = tid & 63;
    int mt = (wv & 1) * 32, nt = (wv >> 1) * 32;
    floatx4 acc[2][2] = {};
    int r = tid >> 2, cS = (tid & 3) * 16;  // row, short-col within 64-wide k tile
    int arow = m0 + r; if (arow >= M) arow = M - 1;
    const bf16* aptr = A + (size_t)arow * K + cS;
    const bf16* bptr = Bt + (size_t)(n0 + r) * K + cS;
    short* asl = &At[r * 72 + cS];
    short* bsl = &Bs[r * 72 + cS];
    int lrow = lane & 15, lq = lane >> 4;
    const short* aRd = &At[(mt + lrow) * 72 + lq * 8];
    const short* bRd = &Bs[(nt + lrow) * 72 + lq * 8];
    for (int k0 = 0; k0 < K; k0 += 64) {
        *(uint4*)asl       = *(const uint4*)(aptr);
        *(uint4*)(asl + 8) = *(const uint4*)(aptr + 8);
        *(uint4*)bsl       = *(const uint4*)(bptr);
        *(uint4*)(bsl + 8) = *(const uint4*)(bptr + 8);
        aptr += 64; bptr += 64;
        __syncthreads();
        shortx8 a00 = *(const shortx8*)(aRd);
        shortx8 a10 = *(const shortx8*)(aRd + 16 * 72);
        shortx8 b00 = *(const shortx8*)(bRd);
        shortx8 b10 = *(const shortx8*)(bRd + 16 * 72);
        shortx8 a01 = *(const shortx8*)(aRd + 32);
        shortx8 a11 = *(const shortx8*)(aRd + 16 * 72 + 32);
        shortx8 b01 = *(const shortx8*)(bRd + 32);
        shortx8 b11 = *(const shortx8*)(bRd + 16 * 72 + 32);
        acc[0][0] = __builtin_amdgcn_mfma_f32_16x16x32_bf16(a00, b00, acc[0][0], 0, 0, 0);
        acc[0][1] = __builtin_amdgcn_mfma_f32_16x16x32_bf16(a00, b10, acc[0][1], 0, 0, 0);
        acc[1][0] = __builtin_amdgcn_mfma_f32_16x16x32_bf16(a10, b00, acc[1][0], 0, 0, 0);
        acc[1][1] = __builtin_amdgcn_mfma_f32_16x16x32_bf16(a10, b10, acc[1][1], 0, 0, 0);
        acc[0][0] = __builtin_amdgcn_mfma_f32_16x16x32_bf16(a01, b01, acc[0][0], 0, 0, 0);
        acc[0][1] = __builtin_amdgcn_mfma_f32_16x16x32_bf16(a01, b11, acc[0][1], 0, 0, 0);
        acc[1][0] = __builtin_amdgcn_mfma_f32_16x16x32_bf16(a11, b01, acc[1][0], 0, 0, 0);
        acc[1][1] = __builtin_amdgcn_mfma_f32_16x16x32_bf16(a11, b11, acc[1][1], 0, 0, 0);
        __syncthreads();
    }
    int colb = n0 + nt + lrow;
    for (int mi = 0; mi < 2; mi++) {
        for (int ni = 0; ni < 2; ni++) {
            int cc = colb + ni * 16;
            #pragma unroll
            for (int rg = 0; rg < 4; rg++) {
                int rr = m0 + mt + mi * 16 + lq * 4 + rg;
                if (rr < M) {
                    float u = acc[mi][ni][rg] + bias[cc];
                    if (mode == 1) {
                        float g = 0.5f * u * (1.0f + erff(u * 0.70710678118f));
                        outB[(size_t)rr * N + cc] = f2b(g);
                    } else if (mode == 2) {
                        xio[(size_t)rr * N + cc] += gamma[cc] * u;
                    } else {
                        outB[(size_t)rr * N + cc] = f2b(u);
                    }
                }
            }
        }
    }
}

// ---------------- qk prep: RMS norm + RoPE, split to head-major bf16 ----------------
__global__ __launch_bounds__(256) void k_qkprep(
    const bf16* __restrict__ qkv,
    const float* __restrict__ qnw, const float* __restrict__ knw,
    const float* __restrict__ ctab, const float* __restrict__ stab, int posMod,
    bf16* __restrict__ qh, bf16* __restrict__ kh, bf16* __restrict__ vh) {
    int gw = blockIdx.x * 4 + (threadIdx.x >> 6);
    int lane = threadIdx.x & 63;
    if (gw >= T_TOK * H_HEADS) return;
    int t = gw / H_HEADS, h = gw - t * H_HEADS;
    size_t base = (size_t)t * 2304 + h * 64 + lane;
    float q = b2f(qkv[base]), k = b2f(qkv[base + 768]), v = b2f(qkv[base + 1536]);
    float sq = q * q, sk = k * k;
    for (int o = 32; o; o >>= 1) { sq += __shfl_xor(sq, o, 64); sk += __shfl_xor(sk, o, 64); }
    q = q * rsqrtf(sq * (1.0f / 64.0f) + 1e-6f) * qnw[lane];
    k = k * rsqrtf(sk * (1.0f / 64.0f) + 1e-6f) * knw[lane];
    int pos = t % posMod;
    float cv = ctab[pos * 64 + lane];
    float sv = stab[pos * 64 + lane];
    float qp = __shfl_xor(q, 16, 64);
    float kp = __shfl_xor(k, 16, 64);
    float sgn = (lane & 16) ? 1.0f : -1.0f;
    float qo = q * cv + sgn * qp * sv;
    float ko = k * cv + sgn * kp * sv;
    size_t oidx = ((size_t)h * T_TOK + t) * 64 + lane;
    qh[oidx] = f2b(qo);
    kh[oidx] = f2b(ko);
    vh[oidx] = f2b(v);
}

// ---------------- attention: 8 q-rows per block, scores in LDS ----------------
__global__ __launch_bounds__(256) void k_attn(
    const bf16* __restrict__ qh, const bf16* __restrict__ kh, const bf16* __restrict__ vh,
    const float* __restrict__ mask, bf16* __restrict__ out, int nk) {
    __shared__ float sc[8 * SP];
    __shared__ float kt[32 * 68];
    __shared__ float qt[8 * 68];
    int h = blockIdx.y;
    int base = blockIdx.z * nk;
    int q0 = blockIdx.x * 8;
    int tid = threadIdx.x;
    // stage Q tile (vectorized: 4 bf16 -> float4)
    for (int idx = tid; idx < 8 * 16; idx += 256) {
        int qi2 = idx >> 4, d = (idx & 15) * 4;
        int qr = q0 + qi2;
        float4 v = {0.f, 0.f, 0.f, 0.f};
        if (qr < nk) {
            ushort4 u = *(const ushort4*)(qh + ((size_t)h * T_TOK + base + qr) * 64 + d);
            v.x = b2f(*(bf16*)&u.x); v.y = b2f(*(bf16*)&u.y);
            v.z = b2f(*(bf16*)&u.z); v.w = b2f(*(bf16*)&u.w);
        }
        *(float4*)&qt[qi2 * 68 + d] = v;
    }
    __syncthreads();
    int qi = tid >> 5, kk = tid & 31;
    int nkt = (nk + 31) >> 5;
    for (int ktile = 0; ktile < nkt; ktile++) {
        __syncthreads();
        for (int idx = tid; idx < 32 * 16; idx += 256) {
            int kr = idx >> 4, d = (idx & 15) * 4;
            int gk = ktile * 32 + kr;
            float4 v = {0.f, 0.f, 0.f, 0.f};
            if (gk < nk) {
                ushort4 u = *(const ushort4*)(kh + ((size_t)h * T_TOK + base + gk) * 64 + d);
                v.x = b2f(*(bf16*)&u.x); v.y = b2f(*(bf16*)&u.y);
                v.z = b2f(*(bf16*)&u.z); v.w = b2f(*(bf16*)&u.w);
            }
            *(float4*)&kt[kr * 68 + d] = v;
        }
        __syncthreads();
        int gk = ktile * 32 + kk;
        if (gk < nk) {
            float acc = 0.f;
            const float* qr = &qt[qi * 68];
            const float* kr = &kt[kk * 68];
            #pragma unroll
            for (int d = 0; d < 64; d += 4) {
                float4 qv = *(const float4*)&qr[d];
                float4 kv = *(const float4*)&kr[d];
                acc += qv.x * kv.x + qv.y * kv.y + qv.z * kv.z + qv.w * kv.w;
            }
            float bias = (1.0f - mask[base + gk]) * -10000.0f;
            sc[qi * SP + gk] = acc * 0.125f + bias;
        }
    }
    __syncthreads();
    // softmax: 32 lanes own one q row (same half-wave -> width-32 shuffles ok)
    int l = tid & 31;
    float m = -3.0e38f;
    for (int k = l; k < nk; k += 32) m = fmaxf(m, sc[qi * SP + k]);
    for (int o = 16; o; o >>= 1) m = fmaxf(m, __shfl_xor(m, o, 32));
    float ssum = 0.f;
    for (int k = l; k < nk; k += 32) { float e = __expf(sc[qi * SP + k] - m); sc[qi * SP + k] = e; ssum += e; }
    for (int o = 16; o; o >>= 1) ssum += __shfl_xor(ssum, o, 32);
    float inv = 1.0f / ssum;
    // PV: each lane owns dims (2l, 2l+1) of its q row; 4x unrolled
    int qrow = q0 + qi;
    if (qrow >= nk) return;
    const __hip_bfloat162* v2 = (const __hip_bfloat162*)(vh + ((size_t)h * T_TOK + base) * 64);
    const float* srow = &sc[qi * SP];
    float a0 = 0.f, a1 = 0.f;
    int nk4 = nk & ~3;
    for (int k = 0; k < nk4; k += 4) {
        float4 p = *(const float4*)&srow[k];
        __hip_bfloat162 w0 = v2[(k + 0) * 32 + l];
        __hip_bfloat162 w1 = v2[(k + 1) * 32 + l];
        __hip_bfloat162 w2 = v2[(k + 2) * 32 + l];
        __hip_bfloat162 w3 = v2[(k + 3) * 32 + l];
        float2 f0 = __bfloat1622float2(w0);
        float2 f1 = __bfloat1622float2(w1);
        float2 f2 = __bfloat1622float2(w2);
        float2 f3 = __bfloat1622float2(w3);
        a0 += p.x * f0.x + p.y * f1.x + p.z * f2.x + p.w * f3.x;
        a1 += p.x * f0.y + p.y * f1.y + p.z * f2.y + p.w * f3.y;
    }
    for (int k = nk4; k < nk; k++) {
        float p = srow[k];
        float2 vf = __bfloat1622float2(v2[k * 32 + l]);
        a0 += p * vf.x; a1 += p * vf.y;
    }
    size_t ob = (size_t)(base + qrow) * C_DIM + h * 64 + l * 2;
    out[ob] = f2b(a0 * inv);
    out[ob + 1] = f2b(a1 * inv);
}

// ---------------- output assembly at OUT layers (f32 out) ----------------
__global__ __launch_bounds__(256) void k_output(
    const float* __restrict__ xF, const bf16* __restrict__ lxB,
    const float* __restrict__ fw, const float* __restrict__ fb, float* __restrict__ dst) {
    int b = blockIdx.x;                 // 0..1151
    int s = b / 576, nn = b - s * 576;
    int t = s * NLOC + nn + 1;          // skip token 0
    const float* xr = xF + (size_t)t * C_DIM;
    float sum = 0.f, s2 = 0.f;
    for (int c = threadIdx.x; c < C_DIM; c += 256) { float v = xr[c]; sum += v; s2 += v * v; }
    __shared__ float red[8];
    for (int o = 32; o; o >>= 1) { sum += __shfl_xor(sum, o, 64); s2 += __shfl_xor(s2, o, 64); }
    if ((threadIdx.x & 63) == 0) { red[threadIdx.x >> 6] = sum; red[4 + (threadIdx.x >> 6)] = s2; }
    __syncthreads();
    sum = red[0] + red[1] + red[2] + red[3];
    s2 = red[4] + red[5] + red[6] + red[7];
    float mean = sum * (1.0f / C_DIM);
    float var = s2 * (1.0f / C_DIM) - mean * mean;
    if (var < 0.f) var = 0.f;
    float inv = rsqrtf(var + 1e-6f);
    float* orow = dst + (size_t)b * 1536;
    const bf16* lr = lxB + (size_t)t * C_DIM;
    for (int c = threadIdx.x; c < C_DIM; c += 256) {
        orow[c] = b2f(lr[c]);
        float v = (xr[c] - mean) * inv * fw[c] + fb[c];
        orow[768 + c] = v;
    }
}

// ---------------- camera tokens (layer 11, no final LN) ----------------
__global__ void k_cam(const float* __restrict__ xF, const bf16* __restrict__ lxB,
                      float* __restrict__ dst) {
    for (int idx = threadIdx.x; idx < 2 * 1536; idx += 256) {
        int s = idx / 1536, c = idx - s * 1536;
        int t = s * NLOC;
        float v = (c < 768) ? b2f(lxB[(size_t)t * 768 + c]) : xF[(size_t)t * 768 + (c - 768)];
        dst[idx] = v;
    }
}

extern "C" void kernel_launch(void* const* d_in, const int* in_sizes, int n_in,
                              void* d_out, int out_size, void* d_ws, size_t ws_size,
                              hipStream_t stream) {
    const float* xin  = (const float*)d_in[0];
    const float* rcl  = (const float*)d_in[1];
    const float* rsl  = (const float*)d_in[2];
    const float* rcg  = (const float*)d_in[3];
    const float* rsg  = (const float*)d_in[4];
    const float* kvl  = (const float*)d_in[5];
    const float* kvg  = (const float*)d_in[6];
    const float* cam  = (const float*)d_in[7];
    const float* qkvw = (const float*)d_in[8];
    const float* qkvb = (const float*)d_in[9];
    const float* qnw  = (const float*)d_in[10];
    const float* knw  = (const float*)d_in[11];
    const float* pw   = (const float*)d_in[12];
    const float* pb   = (const float*)d_in[13];
    const float* ls1  = (const float*)d_in[14];
    const float* ls2  = (const float*)d_in[15];
    const float* n1w  = (const float*)d_in[16];
    const float* n1b  = (const float*)d_in[17];
    const float* n2w  = (const float*)d_in[18];
    const float* n2b  = (const float*)d_in[19];
    const float* f1w  = (const float*)d_in[20];
    const float* f1b  = (const float*)d_in[21];
    const float* f2w  = (const float*)d_in[22];
    const float* f2b_ = (const float*)d_in[23];
    const float* fnw  = (const float*)d_in[24];
    const float* fnb  = (const float*)d_in[25];

    // Workspace (~33.9 MB):
    //   xF   f32 [1154][768]
    //   bufA bf16 union{ qkv[1154][2304], mlp[1154][3072] }
    //   qhb/khb/vhb bf16 [12][1154][64]
    //   hbuf bf16 [1154][768]
    //   lxB  bf16 [1154][768]
    //   wB   bf16 [NWTOT]  (per-layer converted weights: qkv|proj|fc1|fc2)
    char* ws = (char*)d_ws;
    const size_t TC = (size_t)T_TOK * C_DIM;                 // 886,272
    float* xF  = (float*)ws; ws += TC * 4;
    bf16* bufA = (bf16*)ws;  ws += (size_t)T_TOK * 3072 * 2;
    bf16* qhb  = (bf16*)ws;  ws += TC * 2;
    bf16* khb  = (bf16*)ws;  ws += TC * 2;
    bf16* vhb  = (bf16*)ws;  ws += TC * 2;
    bf16* hbuf = (bf16*)ws;  ws += TC * 2;
    bf16* lxB  = (bf16*)ws;  ws += TC * 2;
    bf16* wB   = (bf16*)ws;  ws += NWTOT * 2;
    (void)ws_size; (void)n_in; (void)in_sizes; (void)out_size;

    float* out_b = (float*)d_out;

    k_init<<<(int)((TC + 255) / 256), 256, 0, stream>>>(xin, cam, xF, (int)TC);

    int outIdx = 0;
    for (int i = 0; i < 12; i++) {
        bool isGlobal = (i & 1);
        // weights -> bf16 (one fused launch, 7.08M elems)
        k_wconv<<<3456, 256, 0, stream>>>(
            qkvw + (size_t)i * NQ, pw + (size_t)i * NP,
            f1w + (size_t)i * NF1, f2w + (size_t)i * NF2, wB);
        // LN1
        k_ln<<<T_TOK, 256, 0, stream>>>(xF, n1w + (size_t)i * 768, n1b + (size_t)i * 768, hbuf);
        // QKV gemm -> bf16 (bufA)
        k_gemm<<<19 * 36, 256, 0, stream>>>(hbuf, wB + WQ,
            qkvb + (size_t)i * 2304, nullptr, bufA, nullptr, T_TOK, 2304, 768, 19, 3);
        // rms + rope + head split
        k_qkprep<<<(T_TOK * H_HEADS) / 4, 256, 0, stream>>>(bufA,
            qnw + (size_t)i * 64, knw + (size_t)i * 64,
            isGlobal ? rcg : rcl, isGlobal ? rsg : rsl, isGlobal ? 1154 : 577,
            qhb, khb, vhb);
        // attention -> hbuf
        if (isGlobal)
            k_attn<<<dim3(145, 12, 1), 256, 0, stream>>>(qhb, khb, vhb, kvg, hbuf, 1154);
        else
            k_attn<<<dim3(73, 12, 2), 256, 0, stream>>>(qhb, khb, vhb, kvl, hbuf, 577);
        // proj + residual (x += ls1*(o@pw^T+pb))
        k_gemm<<<19 * 12, 256, 0, stream>>>(hbuf, wB + WP,
            pb + (size_t)i * 768, ls1 + (size_t)i * 768, nullptr, xF, T_TOK, 768, 768, 19, 2);
        // LN2
        k_ln<<<T_TOK, 256, 0, stream>>>(xF, n2w + (size_t)i * 768, n2b + (size_t)i * 768, hbuf);
        // fc1 + gelu -> bufA (bf16)
        k_gemm<<<19 * 48, 256, 0, stream>>>(hbuf, wB + WF1,
            f1b + (size_t)i * 3072, nullptr, bufA, nullptr, T_TOK, 3072, 768, 19, 1);
        // fc2 + residual
        k_gemm<<<19 * 12, 256, 0, stream>>>(bufA, wB + WF2,
            f2b_ + (size_t)i * 768, ls2 + (size_t)i * 768, nullptr, xF, T_TOK, 768, 3072, 19, 2);

        // snapshot local_x
        if (i == 2 || i == 4 || i == 8 || i == 10)
            k_cast<<<(int)((TC + 255) / 256), 256, 0, stream>>>(xF, lxB, (int)TC);

        if (i == 2 || i == 5 || i == 8 || i == 11) {
            k_output<<<1152, 256, 0, stream>>>(xF, lxB, fnw, fnb, out_b + (size_t)outIdx * OUT_PER);
            if (i == 11)
                k_cam<<<1, 256, 0, stream>>>(xF, lxB, out_b + 4ull * OUT_PER);
            outIdx++;
        }
    }
}

// Round 2
// 2168.448 us; speedup vs baseline: 1.7482x; 1.7482x over previous
//
#include <hip/hip_runtime.h>
#include <hip/hip_bf16.h>
#include <math.h>

typedef __hip_bfloat16 bf16;
typedef __attribute__((ext_vector_type(4))) float floatx4;
typedef __attribute__((ext_vector_type(8))) short shortx8;

#define T_TOK 1154
#define C_DIM 768
#define H_HEADS 12
#define NLOC 577
#define OUT_PER 1769472  // 2*576*1536

// per-layer weight element counts (row-major [O,K])
#define NQ  1769472ull   // 2304*768
#define NP  589824ull    // 768*768
#define NF1 2359296ull   // 3072*768
#define NF2 2359296ull   // 768*3072
#define NWTOT 7077888ull // NQ+NP+NF1+NF2
// offsets into per-layer bf16 weight buffer
#define WQ  0ull
#define WP  1769472ull
#define WF1 2359296ull
#define WF2 4718592ull

static __device__ __forceinline__ float b2f(bf16 v) { return __bfloat162float(v); }
static __device__ __forceinline__ bf16 f2b(float v) { return __float2bfloat16(v); }

// ---------------- init: x (f32) -> f32 residual, camera token splice ----------------
__global__ void k_init(const float* __restrict__ xin, const float* __restrict__ cam,
                       float* __restrict__ xF, int total) {
    int idx = blockIdx.x * 256 + threadIdx.x;
    if (idx >= total) return;
    int t = idx / C_DIM, c = idx - t * C_DIM;
    int s = t / NLOC, n = t - s * NLOC;
    float v = (n == 0) ? cam[s * C_DIM + c] : xin[idx];
    xF[idx] = v;
}

// ---------------- cast f32 residual -> bf16 snapshot ----------------
__global__ void k_cast(const float* __restrict__ src, bf16* __restrict__ dst, int total) {
    int idx = blockIdx.x * 256 + threadIdx.x;
    if (idx < total) dst[idx] = f2b(src[idx]);
}

// ---------------- per-layer weight convert: f32 -> bf16 (4 mats fused) ----------------
__global__ __launch_bounds__(256) void k_wconv(
    const float* __restrict__ wq, const float* __restrict__ wp,
    const float* __restrict__ wf1, const float* __restrict__ wf2,
    bf16* __restrict__ dst) {
    size_t e = ((size_t)blockIdx.x * 256 + threadIdx.x) * 8;
    if (e >= NWTOT) return;
    const float* src; size_t off;
    if (e < WP)       { src = wq;  off = e; }
    else if (e < WF1) { src = wp;  off = e - WP; }
    else if (e < WF2) { src = wf1; off = e - WF1; }
    else              { src = wf2; off = e - WF2; }
    float4 a = *(const float4*)(src + off);
    float4 b = *(const float4*)(src + off + 4);
    bf16 pk[8];
    pk[0] = f2b(a.x); pk[1] = f2b(a.y); pk[2] = f2b(a.z); pk[3] = f2b(a.w);
    pk[4] = f2b(b.x); pk[5] = f2b(b.y); pk[6] = f2b(b.z); pk[7] = f2b(b.w);
    *(shortx8*)(dst + e) = *(shortx8*)pk;
}

// ---------------- LayerNorm: f32 residual -> bf16 ----------------
__global__ __launch_bounds__(256) void k_ln(const float* __restrict__ xF,
                                            const float* __restrict__ w, const float* __restrict__ b,
                                            bf16* __restrict__ out) {
    int t = blockIdx.x;
    const float* xr = xF + (size_t)t * C_DIM;
    float s = 0.f, s2 = 0.f;
    for (int c = threadIdx.x; c < C_DIM; c += 256) { float v = xr[c]; s += v; s2 += v * v; }
    __shared__ float red[8];
    for (int o = 32; o; o >>= 1) { s += __shfl_xor(s, o, 64); s2 += __shfl_xor(s2, o, 64); }
    int wv = threadIdx.x >> 6;
    if ((threadIdx.x & 63) == 0) { red[wv] = s; red[4 + wv] = s2; }
    __syncthreads();
    s = red[0] + red[1] + red[2] + red[3];
    s2 = red[4] + red[5] + red[6] + red[7];
    float mean = s * (1.0f / C_DIM);
    float var = s2 * (1.0f / C_DIM) - mean * mean;
    if (var < 0.f) var = 0.f;
    float inv = rsqrtf(var + 1e-6f);
    bf16* orow = out + (size_t)t * C_DIM;
    for (int c = threadIdx.x; c < C_DIM; c += 256) {
        float v = (xr[c] - mean) * inv * w[c] + b[c];
        orow[c] = f2b(v);
    }
}

// ---------------- GEMM: out[M,N] = A[M,K](bf16) x Bt[N,K](bf16)^T ----------------
// 64x64 tile, K-step 64, XCD-bijective-swizzled 1D grid.
// mode 1: outB = gelu_exact(acc + bias)         (bf16 out)
// mode 2: xio += gamma * (acc + bias)           (f32 residual in-place)
// mode 3: outB = acc + bias                     (bf16 out)
__global__ __launch_bounds__(256) void k_gemm(
    const bf16* __restrict__ A, const bf16* __restrict__ Bt,
    const float* __restrict__ bias, const float* __restrict__ gamma,
    bf16* __restrict__ outB, float* __restrict__ xio,
    int M, int N, int K, int mB, int mode) {
    __shared__ short At[64 * 72];
    __shared__ short Bs[64 * 72];
    // bijective XCD swizzle (m204 form): each XCD owns a contiguous lid2 chunk
    int nwg = gridDim.x;
    int lid = blockIdx.x;
    int qd = nwg >> 3, rm = nwg & 7;
    int xcd = lid & 7, pos = lid >> 3;
    int lid2 = (xcd < rm ? xcd * (qd + 1) : rm * (qd + 1) + (xcd - rm) * qd) + pos;
    int mI = lid2 % mB, nI = lid2 / mB;
    int m0 = mI * 64, n0 = nI * 64;
    int tid = threadIdx.x;
    int wv = tid >> 6, lane = tid & 63;
    int mt = (wv & 1) * 32, nt = (wv >> 1) * 32;
    floatx4 acc[2][2] = {};
    int r = tid >> 2, cS = (tid & 3) * 16;  // row, short-col within 64-wide k tile
    int arow = m0 + r; if (arow >= M) arow = M - 1;
    const bf16* aptr = A + (size_t)arow * K + cS;
    const bf16* bptr = Bt + (size_t)(n0 + r) * K + cS;
    short* asl = &At[r * 72 + cS];
    short* bsl = &Bs[r * 72 + cS];
    int lrow = lane & 15, lq = lane >> 4;
    const short* aRd = &At[(mt + lrow) * 72 + lq * 8];
    const short* bRd = &Bs[(nt + lrow) * 72 + lq * 8];
    for (int k0 = 0; k0 < K; k0 += 64) {
        *(uint4*)asl       = *(const uint4*)(aptr);
        *(uint4*)(asl + 8) = *(const uint4*)(aptr + 8);
        *(uint4*)bsl       = *(const uint4*)(bptr);
        *(uint4*)(bsl + 8) = *(const uint4*)(bptr + 8);
        aptr += 64; bptr += 64;
        __syncthreads();
        shortx8 a00 = *(const shortx8*)(aRd);
        shortx8 a10 = *(const shortx8*)(aRd + 16 * 72);
        shortx8 b00 = *(const shortx8*)(bRd);
        shortx8 b10 = *(const shortx8*)(bRd + 16 * 72);
        shortx8 a01 = *(const shortx8*)(aRd + 32);
        shortx8 a11 = *(const shortx8*)(aRd + 16 * 72 + 32);
        shortx8 b01 = *(const shortx8*)(bRd + 32);
        shortx8 b11 = *(const shortx8*)(bRd + 16 * 72 + 32);
        acc[0][0] = __builtin_amdgcn_mfma_f32_16x16x32_bf16(a00, b00, acc[0][0], 0, 0, 0);
        acc[0][1] = __builtin_amdgcn_mfma_f32_16x16x32_bf16(a00, b10, acc[0][1], 0, 0, 0);
        acc[1][0] = __builtin_amdgcn_mfma_f32_16x16x32_bf16(a10, b00, acc[1][0], 0, 0, 0);
        acc[1][1] = __builtin_amdgcn_mfma_f32_16x16x32_bf16(a10, b10, acc[1][1], 0, 0, 0);
        acc[0][0] = __builtin_amdgcn_mfma_f32_16x16x32_bf16(a01, b01, acc[0][0], 0, 0, 0);
        acc[0][1] = __builtin_amdgcn_mfma_f32_16x16x32_bf16(a01, b11, acc[0][1], 0, 0, 0);
        acc[1][0] = __builtin_amdgcn_mfma_f32_16x16x32_bf16(a11, b01, acc[1][0], 0, 0, 0);
        acc[1][1] = __builtin_amdgcn_mfma_f32_16x16x32_bf16(a11, b11, acc[1][1], 0, 0, 0);
        __syncthreads();
    }
    int colb = n0 + nt + lrow;
    for (int mi = 0; mi < 2; mi++) {
        for (int ni = 0; ni < 2; ni++) {
            int cc = colb + ni * 16;
            #pragma unroll
            for (int rg = 0; rg < 4; rg++) {
                int rr = m0 + mt + mi * 16 + lq * 4 + rg;
                if (rr < M) {
                    float u = acc[mi][ni][rg] + bias[cc];
                    if (mode == 1) {
                        float g = 0.5f * u * (1.0f + erff(u * 0.70710678118f));
                        outB[(size_t)rr * N + cc] = f2b(g);
                    } else if (mode == 2) {
                        xio[(size_t)rr * N + cc] += gamma[cc] * u;
                    } else {
                        outB[(size_t)rr * N + cc] = f2b(u);
                    }
                }
            }
        }
    }
}

// ---------------- qk prep: RMS norm + RoPE, split to head-major bf16 ----------------
__global__ __launch_bounds__(256) void k_qkprep(
    const bf16* __restrict__ qkv,
    const float* __restrict__ qnw, const float* __restrict__ knw,
    const float* __restrict__ ctab, const float* __restrict__ stab, int posMod,
    bf16* __restrict__ qh, bf16* __restrict__ kh, bf16* __restrict__ vh) {
    int gw = blockIdx.x * 4 + (threadIdx.x >> 6);
    int lane = threadIdx.x & 63;
    if (gw >= T_TOK * H_HEADS) return;
    int t = gw / H_HEADS, h = gw - t * H_HEADS;
    size_t base = (size_t)t * 2304 + h * 64 + lane;
    float q = b2f(qkv[base]), k = b2f(qkv[base + 768]), v = b2f(qkv[base + 1536]);
    float sq = q * q, sk = k * k;
    for (int o = 32; o; o >>= 1) { sq += __shfl_xor(sq, o, 64); sk += __shfl_xor(sk, o, 64); }
    q = q * rsqrtf(sq * (1.0f / 64.0f) + 1e-6f) * qnw[lane];
    k = k * rsqrtf(sk * (1.0f / 64.0f) + 1e-6f) * knw[lane];
    int pos = t % posMod;
    float cv = ctab[pos * 64 + lane];
    float sv = stab[pos * 64 + lane];
    float qp = __shfl_xor(q, 16, 64);
    float kp = __shfl_xor(k, 16, 64);
    float sgn = (lane & 16) ? 1.0f : -1.0f;
    float qo = q * cv + sgn * qp * sv;
    float ko = k * cv + sgn * kp * sv;
    size_t oidx = ((size_t)h * T_TOK + t) * 64 + lane;
    qh[oidx] = f2b(qo);
    kh[oidx] = f2b(ko);
    vh[oidx] = f2b(v);
}

// ---------------- attention: flash-style MFMA ----------------
// Block: 256 thr (4 waves). One head, 64 q-rows (16 per wave).
// Per 64-wide k-tile: stage K [64][72] LDS + V transposed [d][k] [64][72] LDS,
// QK^T via mfma_16x16x32_bf16, online softmax, P->bf16 via per-wave LDS, PV via MFMA.
__global__ __launch_bounds__(256) void k_attn2(
    const bf16* __restrict__ qh, const bf16* __restrict__ kh, const bf16* __restrict__ vh,
    const float* __restrict__ mask, bf16* __restrict__ out, int nk) {
    __shared__ short Ks[64 * 72];
    __shared__ short Vs[64 * 72];      // V^T tile: [d][k]
    __shared__ short Ps[4][16 * 72];   // per-wave P (bf16)
    __shared__ float bias_s[64];
    int h = blockIdx.y;
    int base = blockIdx.z * nk;
    int tid = threadIdx.x;
    int wv = tid >> 6, lane = tid & 63;
    int lr = lane & 15, lq = lane >> 4;
    int q0 = blockIdx.x * 64 + wv * 16;
    // Q fragments: lane holds Q[q0+lr][ks*32 + lq*8 + j]
    shortx8 qf[2];
    {
        int qr = q0 + lr; if (qr >= nk) qr = nk - 1;
        const bf16* qp = qh + ((size_t)h * T_TOK + base + qr) * 64 + lq * 8;
        qf[0] = *(const shortx8*)(qp);
        qf[1] = *(const shortx8*)(qp + 32);
    }
    float mrow[4] = {-3.0e38f, -3.0e38f, -3.0e38f, -3.0e38f};
    float lrow[4] = {0.f, 0.f, 0.f, 0.f};
    floatx4 accO[4] = {};   // [d-tile]; rows = lq*4+reg, col = dt*16+lr
    short* pbuf = &Ps[wv][0];
    int nkt = (nk + 63) >> 6;
    for (int kt0 = 0; kt0 < nkt; kt0++) {
        int kbase = kt0 * 64;
        __syncthreads();  // protect LDS from previous iteration's readers
        // stage K tile: [k][d] -> Ks[k][d] (b128 writes, bank-balanced)
        for (int idx = tid; idx < 64 * 8; idx += 256) {
            int kr = idx >> 3, seg = idx & 7;
            int gk = kbase + kr;
            shortx8 v = {};
            if (gk < nk) v = *(const shortx8*)(kh + ((size_t)h * T_TOK + base + gk) * 64 + seg * 8);
            *(shortx8*)&Ks[kr * 72 + seg * 8] = v;
        }
        // stage V tile transposed: global [k][d] -> Vs[d][k]
        // mapping: kr = lane (so per-j writes hit all 32 banks 2-way = free)
        for (int idx = tid; idx < 64 * 8; idx += 256) {
            int kr = idx & 63, seg = idx >> 6;
            int gk = kbase + kr;
            shortx8 v = {};
            if (gk < nk) v = *(const shortx8*)(vh + ((size_t)h * T_TOK + base + gk) * 64 + seg * 8);
            bf16* vb = (bf16*)&v;
            #pragma unroll
            for (int j = 0; j < 8; j++)
                Vs[(seg * 8 + j) * 72 + kr] = *(short*)&vb[j];
        }
        // stage mask bias
        if (tid < 64) {
            int gk = kbase + tid;
            bias_s[tid] = (gk < nk) ? (1.0f - mask[base + gk]) * -10000.0f : -30000.0f;
        }
        __syncthreads();
        // QK^T: 4 n-tiles of 16 k-cols
        floatx4 s[4];
        #pragma unroll
        for (int nt = 0; nt < 4; nt++) {
            floatx4 accS = {};
            shortx8 k0 = *(const shortx8*)&Ks[(nt * 16 + lr) * 72 + lq * 8];
            shortx8 k1 = *(const shortx8*)&Ks[(nt * 16 + lr) * 72 + 32 + lq * 8];
            accS = __builtin_amdgcn_mfma_f32_16x16x32_bf16(qf[0], k0, accS, 0, 0, 0);
            accS = __builtin_amdgcn_mfma_f32_16x16x32_bf16(qf[1], k1, accS, 0, 0, 0);
            s[nt] = accS;
        }
        // scale + bias, tile row-max
        float tmax[4] = {-3.0e38f, -3.0e38f, -3.0e38f, -3.0e38f};
        #pragma unroll
        for (int nt = 0; nt < 4; nt++) {
            float bv = bias_s[nt * 16 + lr];
            #pragma unroll
            for (int rg = 0; rg < 4; rg++) {
                float sv = s[nt][rg] * 0.125f + bv;
                s[nt][rg] = sv;
                tmax[rg] = fmaxf(tmax[rg], sv);
            }
        }
        #pragma unroll
        for (int rg = 0; rg < 4; rg++) {
            for (int o = 1; o < 16; o <<= 1) tmax[rg] = fmaxf(tmax[rg], __shfl_xor(tmax[rg], o, 16));
        }
        float fac[4], tsum[4] = {0.f, 0.f, 0.f, 0.f};
        #pragma unroll
        for (int rg = 0; rg < 4; rg++) {
            float mn = fmaxf(mrow[rg], tmax[rg]);
            fac[rg] = __expf(mrow[rg] - mn);
            mrow[rg] = mn;
        }
        #pragma unroll
        for (int nt = 0; nt < 4; nt++) {
            #pragma unroll
            for (int rg = 0; rg < 4; rg++) {
                float e = __expf(s[nt][rg] - mrow[rg]);
                s[nt][rg] = e;
                tsum[rg] += e;
            }
        }
        #pragma unroll
        for (int rg = 0; rg < 4; rg++) {
            for (int o = 1; o < 16; o <<= 1) tsum[rg] += __shfl_xor(tsum[rg], o, 16);
            lrow[rg] = lrow[rg] * fac[rg] + tsum[rg];
        }
        // rescale O
        #pragma unroll
        for (int dt = 0; dt < 4; dt++)
            #pragma unroll
            for (int rg = 0; rg < 4; rg++) accO[dt][rg] *= fac[rg];
        // P -> bf16 into per-wave LDS [row][col] pitch 72
        #pragma unroll
        for (int nt = 0; nt < 4; nt++) {
            #pragma unroll
            for (int rg = 0; rg < 4; rg++) {
                bf16 pv = f2b(s[nt][rg]);
                pbuf[(lq * 4 + rg) * 72 + nt * 16 + lr] = *(short*)&pv;
            }
        }
        // PV: A = P [16 x 64], B = Vs (V^T) -> accO[dt]
        #pragma unroll
        for (int ks = 0; ks < 2; ks++) {
            shortx8 pf = *(const shortx8*)&pbuf[lr * 72 + ks * 32 + lq * 8];
            #pragma unroll
            for (int dt = 0; dt < 4; dt++) {
                shortx8 vf = *(const shortx8*)&Vs[(dt * 16 + lr) * 72 + ks * 32 + lq * 8];
                accO[dt] = __builtin_amdgcn_mfma_f32_16x16x32_bf16(pf, vf, accO[dt], 0, 0, 0);
            }
        }
    }
    // epilogue
    float invl[4];
    #pragma unroll
    for (int rg = 0; rg < 4; rg++) invl[rg] = 1.0f / lrow[rg];
    #pragma unroll
    for (int rg = 0; rg < 4; rg++) {
        int qr = q0 + lq * 4 + rg;
        if (qr < nk) {
            bf16* orow = out + (size_t)(base + qr) * C_DIM + h * 64 + lr;
            #pragma unroll
            for (int dt = 0; dt < 4; dt++)
                orow[dt * 16] = f2b(accO[dt][rg] * invl[rg]);
        }
    }
}

// ---------------- output assembly at OUT layers (f32 out) ----------------
__global__ __launch_bounds__(256) void k_output(
    const float* __restrict__ xF, const bf16* __restrict__ lxB,
    const float* __restrict__ fw, const float* __restrict__ fb, float* __restrict__ dst) {
    int b = blockIdx.x;                 // 0..1151
    int s = b / 576, nn = b - s * 576;
    int t = s * NLOC + nn + 1;          // skip token 0
    const float* xr = xF + (size_t)t * C_DIM;
    float sum = 0.f, s2 = 0.f;
    for (int c = threadIdx.x; c < C_DIM; c += 256) { float v = xr[c]; sum += v; s2 += v * v; }
    __shared__ float red[8];
    for (int o = 32; o; o >>= 1) { sum += __shfl_xor(sum, o, 64); s2 += __shfl_xor(s2, o, 64); }
    if ((threadIdx.x & 63) == 0) { red[threadIdx.x >> 6] = sum; red[4 + (threadIdx.x >> 6)] = s2; }
    __syncthreads();
    sum = red[0] + red[1] + red[2] + red[3];
    s2 = red[4] + red[5] + red[6] + red[7];
    float mean = sum * (1.0f / C_DIM);
    float var = s2 * (1.0f / C_DIM) - mean * mean;
    if (var < 0.f) var = 0.f;
    float inv = rsqrtf(var + 1e-6f);
    float* orow = dst + (size_t)b * 1536;
    const bf16* lr = lxB + (size_t)t * C_DIM;
    for (int c = threadIdx.x; c < C_DIM; c += 256) {
        orow[c] = b2f(lr[c]);
        float v = (xr[c] - mean) * inv * fw[c] + fb[c];
        orow[768 + c] = v;
    }
}

// ---------------- camera tokens (layer 11, no final LN) ----------------
__global__ void k_cam(const float* __restrict__ xF, const bf16* __restrict__ lxB,
                      float* __restrict__ dst) {
    for (int idx = threadIdx.x; idx < 2 * 1536; idx += 256) {
        int s = idx / 1536, c = idx - s * 1536;
        int t = s * NLOC;
        float v = (c < 768) ? b2f(lxB[(size_t)t * 768 + c]) : xF[(size_t)t * 768 + (c - 768)];
        dst[idx] = v;
    }
}

extern "C" void kernel_launch(void* const* d_in, const int* in_sizes, int n_in,
                              void* d_out, int out_size, void* d_ws, size_t ws_size,
                              hipStream_t stream) {
    const float* xin  = (const float*)d_in[0];
    const float* rcl  = (const float*)d_in[1];
    const float* rsl  = (const float*)d_in[2];
    const float* rcg  = (const float*)d_in[3];
    const float* rsg  = (const float*)d_in[4];
    const float* kvl  = (const float*)d_in[5];
    const float* kvg  = (const float*)d_in[6];
    const float* cam  = (const float*)d_in[7];
    const float* qkvw = (const float*)d_in[8];
    const float* qkvb = (const float*)d_in[9];
    const float* qnw  = (const float*)d_in[10];
    const float* knw  = (const float*)d_in[11];
    const float* pw   = (const float*)d_in[12];
    const float* pb   = (const float*)d_in[13];
    const float* ls1  = (const float*)d_in[14];
    const float* ls2  = (const float*)d_in[15];
    const float* n1w  = (const float*)d_in[16];
    const float* n1b  = (const float*)d_in[17];
    const float* n2w  = (const float*)d_in[18];
    const float* n2b  = (const float*)d_in[19];
    const float* f1w  = (const float*)d_in[20];
    const float* f1b  = (const float*)d_in[21];
    const float* f2w  = (const float*)d_in[22];
    const float* f2b_ = (const float*)d_in[23];
    const float* fnw  = (const float*)d_in[24];
    const float* fnb  = (const float*)d_in[25];

    // Workspace (~33.9 MB)
    char* ws = (char*)d_ws;
    const size_t TC = (size_t)T_TOK * C_DIM;                 // 886,272
    float* xF  = (float*)ws; ws += TC * 4;
    bf16* bufA = (bf16*)ws;  ws += (size_t)T_TOK * 3072 * 2;
    bf16* qhb  = (bf16*)ws;  ws += TC * 2;
    bf16* khb  = (bf16*)ws;  ws += TC * 2;
    bf16* vhb  = (bf16*)ws;  ws += TC * 2;
    bf16* hbuf = (bf16*)ws;  ws += TC * 2;
    bf16* lxB  = (bf16*)ws;  ws += TC * 2;
    bf16* wB   = (bf16*)ws;  ws += NWTOT * 2;
    (void)ws_size; (void)n_in; (void)in_sizes; (void)out_size;

    float* out_b = (float*)d_out;

    k_init<<<(int)((TC + 255) / 256), 256, 0, stream>>>(xin, cam, xF, (int)TC);

    int outIdx = 0;
    for (int i = 0; i < 12; i++) {
        bool isGlobal = (i & 1);
        // weights -> bf16 (one fused launch, 7.08M elems)
        k_wconv<<<3456, 256, 0, stream>>>(
            qkvw + (size_t)i * NQ, pw + (size_t)i * NP,
            f1w + (size_t)i * NF1, f2w + (size_t)i * NF2, wB);
        // LN1
        k_ln<<<T_TOK, 256, 0, stream>>>(xF, n1w + (size_t)i * 768, n1b + (size_t)i * 768, hbuf);
        // QKV gemm -> bf16 (bufA)
        k_gemm<<<19 * 36, 256, 0, stream>>>(hbuf, wB + WQ,
            qkvb + (size_t)i * 2304, nullptr, bufA, nullptr, T_TOK, 2304, 768, 19, 3);
        // rms + rope + head split
        k_qkprep<<<(T_TOK * H_HEADS) / 4, 256, 0, stream>>>(bufA,
            qnw + (size_t)i * 64, knw + (size_t)i * 64,
            isGlobal ? rcg : rcl, isGlobal ? rsg : rsl, isGlobal ? 1154 : 577,
            qhb, khb, vhb);
        // attention -> hbuf (flash-style MFMA)
        if (isGlobal)
            k_attn2<<<dim3(19, 12, 1), 256, 0, stream>>>(qhb, khb, vhb, kvg, hbuf, 1154);
        else
            k_attn2<<<dim3(10, 12, 2), 256, 0, stream>>>(qhb, khb, vhb, kvl, hbuf, 577);
        // proj + residual (x += ls1*(o@pw^T+pb))
        k_gemm<<<19 * 12, 256, 0, stream>>>(hbuf, wB + WP,
            pb + (size_t)i * 768, ls1 + (size_t)i * 768, nullptr, xF, T_TOK, 768, 768, 19, 2);
        // LN2
        k_ln<<<T_TOK, 256, 0, stream>>>(xF, n2w + (size_t)i * 768, n2b + (size_t)i * 768, hbuf);
        // fc1 + gelu -> bufA (bf16)
        k_gemm<<<19 * 48, 256, 0, stream>>>(hbuf, wB + WF1,
            f1b + (size_t)i * 3072, nullptr, bufA, nullptr, T_TOK, 3072, 768, 19, 1);
        // fc2 + residual
        k_gemm<<<19 * 12, 256, 0, stream>>>(bufA, wB + WF2,
            f2b_ + (size_t)i * 768, ls2 + (size_t)i * 768, nullptr, xF, T_TOK, 768, 3072, 19, 2);

        // snapshot local_x
        if (i == 2 || i == 4 || i == 8 || i == 10)
            k_cast<<<(int)((TC + 255) / 256), 256, 0, stream>>>(xF, lxB, (int)TC);

        if (i == 2 || i == 5 || i == 8 || i == 11) {
            k_output<<<1152, 256, 0, stream>>>(xF, lxB, fnw, fnb, out_b + (size_t)outIdx * OUT_PER);
            if (i == 11)
                k_cam<<<1, 256, 0, stream>>>(xF, lxB, out_b + 4ull * OUT_PER);
            outIdx++;
        }
    }
}